// Round 19
// baseline (84.496 us; speedup 1.0000x reference)
//
#include <hip/hip_runtime.h>
#include <hip/hip_bf16.h>
#include <stdint.h>

#define NROWS 32768
#define MCOLS 8192
#define DDIM  256

#define BM 128            // rows per workgroup; block sweeps ALL cols
#define BN 64             // cols per iteration (4 strips x 16)
#define NT (MCOLS/BN)     // 128 iterations
#define NWG (NROWS/BM)    // 256 workgroups = 1 per CU

typedef __attribute__((ext_vector_type(8))) int   int8v;
typedef __attribute__((ext_vector_type(4))) int   int4v;
typedef __attribute__((ext_vector_type(4))) float f32x4;

#define AS1 __attribute__((address_space(1)))
#define AS3 __attribute__((address_space(3)))

// LDS map (bytes): [0,65536) = 8 waves x 8KB private dbuf B
//                  [65536,98304) = Cs (all 8192 cj)
//                  [98304,100352) = Rw[4][128] strip-min merge
#define CS_OFF 65536
#define RW_OFF 98304

// pack 4 f32 -> 4 fp8 e4m3 (OCP) via HW converter (RNE, saturating)
__device__ __forceinline__ uint32_t pk4_fp8(float4 v) {
  int p = __builtin_amdgcn_cvt_pk_fp8_f32(v.x, v.y, 0, false);
  p = __builtin_amdgcn_cvt_pk_fp8_f32(v.z, v.w, p, true);
  return (uint32_t)p;
}
__device__ __forceinline__ f32x4 vmin4(f32x4 x, f32x4 y) {
  f32x4 r;
  r[0] = fminf(x[0], y[0]); r[1] = fminf(x[1], y[1]);
  r[2] = fminf(x[2], y[2]); r[3] = fminf(x[3], y[3]);
  return r;
}

// ---- K1: prep. XqN = row-major fp8 NEGATED (acc C-init = cj -> cj - x.y);
//          Yq = row-major fp8; xhalf = 0.5||x||^2; cbuf = 0.5||y||^2 - psi.
__global__ void k_prep(const float* __restrict__ X, const float* __restrict__ Y,
                       const float* __restrict__ psi,
                       uint32_t* __restrict__ XqN, uint32_t* __restrict__ Yq,
                       float* __restrict__ xhalf, float* __restrict__ cbuf,
                       float* __restrict__ sum_accum)
{
  const int lane = threadIdx.x & 63;
  const int gw = (blockIdx.x * blockDim.x + threadIdx.x) >> 6;
  const int nw = (gridDim.x * blockDim.x) >> 6;
  for (int row = gw; row < NROWS + MCOLS; row += nw) {
    const bool isX = row < NROWS;
    const int r = isX ? row : row - NROWS;
    const float* src = isX ? (X + (size_t)row * DDIM) : (Y + (size_t)r * DDIM);
    float4 v = ((const float4*)src)[lane];
    const uint32_t pk = pk4_fp8(v);
    if (isX) XqN[(size_t)row * 64 + lane] = pk ^ 0x80808080u;   // negate fp8
    else     Yq[(size_t)r * 64 + lane] = pk;
    float s = v.x*v.x + v.y*v.y + v.z*v.z + v.w*v.w;
    #pragma unroll
    for (int m = 32; m >= 1; m >>= 1) s += __shfl_xor(s, m);
    if (lane == 0) {
      if (isX) xhalf[row] = 0.5f * s;
      else     cbuf[r] = 0.5f * s - psi[r];
    }
  }
  if (blockIdx.x == 0 && threadIdx.x == 0) sum_accum[0] = 0.0f;
}

// stage this wave's OWN 16-col strip of tile t_ (4 KB) into its private LDS
// half h_ (0/4096). XOR involution: LDS[c][q] = Yq[col][q ^ (c&15)]; dest
// linear (rule #21). srcG[g] precomputed per-lane for t=0; +t*16384 per tile.
#define STAGE(t_, h_) do {                                                      \
    _Pragma("unroll") for (int _g = 0; _g < 4; ++_g)                            \
      __builtin_amdgcn_global_load_lds(                                         \
          (const AS1 uint32_t*)(srcG[_g] + (size_t)(t_) * 16384),               \
          (AS3 uint32_t*)(ldsB + wbase + (h_) + _g * 1024), 16, 0, 0);          \
  } while (0)

// read this wave's 2 B fragments (4 x ds_read_b128, swizzled) from half h_
#define READF(dst, h_) do {                                                     \
    const char* _b = ldsB + wbase + (h_) + c15 * 256;                           \
    const int4v _l0 = *(const int4v*)(_b + (((w4 * 2 + 0) ^ c15) << 4));        \
    const int4v _h0 = *(const int4v*)(_b + (((w4 * 2 + 1) ^ c15) << 4));        \
    const int4v _l1 = *(const int4v*)(_b + (((8 + w4 * 2 + 0) ^ c15) << 4));    \
    const int4v _h1 = *(const int4v*)(_b + (((8 + w4 * 2 + 1) ^ c15) << 4));    \
    dst[0] = (int8v){_l0[0],_l0[1],_l0[2],_l0[3],_h0[0],_h0[1],_h0[2],_h0[3]};  \
    dst[1] = (int8v){_l1[0],_l1[1],_l1[2],_l1[3],_h1[0],_h1[1],_h1[2],_h1[3]};  \
  } while (0)

// pipelined body t_: CUR holds frags(t_) (read LAST body -> lgkm wait covers
// completed reads); issue reads for frags(t_+1) into NXT; MFMA on CUR with
// C-init = cj; fold min; stage t_+2 into CUR's half.
#define ITER(t_, hC_, CUR, NXT, cjC, cjN) do {                                  \
    asm volatile("s_waitcnt vmcnt(0)" ::: "memory");  /* stage(t_+1) landed */  \
    READF(NXT, (hC_) ^ 4096);                                                   \
    cjN = *(const float*)(ldsB + CS_OFF + ((((t_) + 1) * 64) << 2) + cjo);      \
    const f32x4 _ci = {cjC, cjC, cjC, cjC};                                     \
    f32x4 acc[4];                                                               \
    __builtin_amdgcn_s_setprio(1);                                              \
    _Pragma("unroll") for (int _m = 0; _m < 4; ++_m)                            \
      acc[_m] = __builtin_amdgcn_mfma_scale_f32_16x16x128_f8f6f4(               \
          a[_m][0], CUR[0], _ci, 0, 0, 0, 0x7F, 0, 0x7F);                       \
    _Pragma("unroll") for (int _m = 0; _m < 4; ++_m)                            \
      acc[_m] = __builtin_amdgcn_mfma_scale_f32_16x16x128_f8f6f4(               \
          a[_m][1], CUR[1], acc[_m], 0, 0, 0, 0x7F, 0, 0x7F);                   \
    __builtin_amdgcn_s_setprio(0);                                              \
    _Pragma("unroll") for (int _m = 0; _m < 4; ++_m)                            \
      vmin[_m] = vmin4(vmin[_m], acc[_m]);                                      \
    __builtin_amdgcn_sched_barrier(0);                                          \
    if ((t_) + 2 < NT) STAGE((t_) + 2, hC_);                                    \
  } while (0)

// ---- K2: barrier-free main loop. 8 waves = 2 row-groups x 4 col-strips;
//          A (64 rows) in regs; each wave stages its own strip into private
//          dbuf LDS; frag reads skewed ONE TILE AHEAD into R0/R1 register
//          dbuf so the per-tile lgkm wait covers already-completed reads.
__global__ __attribute__((amdgpu_flat_work_group_size(512, 512),
                          amdgpu_waves_per_eu(2, 2)))
void k_gemm(const uint32_t* __restrict__ XqN, const uint32_t* __restrict__ Yq,
            const float* __restrict__ cbuf, const float* __restrict__ xhalf,
            float* __restrict__ sum_accum)
{
  __shared__ __align__(16) char ldsB[100352 + 8];

  const int brow = blockIdx.x * BM;
  const int tid  = threadIdx.x;
  const int wid  = tid >> 6;
  const int lane = tid & 63;
  const int rg    = wid >> 2;      // 0..1 -> rows rg*64
  const int strip = wid & 3;       // 0..3 -> cols strip*16 within each 64-tile
  const int c15 = lane & 15;
  const int w4  = lane >> 4;
  const int wbase = wid * 8192;    // private 8 KB dbuf
  const int cjo = (strip * 16 + c15) << 2;

  // A fragments (negated fp8): rows brow + rg*64 + m*16 + c15; bytes kc*128+w4*32
  int8v a[4][2];
  {
    const char* aBase = (const char*)XqN + ((size_t)(brow + rg * 64 + c15) << 8) + w4 * 32;
    #pragma unroll
    for (int m = 0; m < 4; ++m)
      #pragma unroll
      for (int kc = 0; kc < 2; ++kc)
        a[m][kc] = *(const int8v*)(aBase + m * 4096 + kc * 128);
  }

  // per-lane stage sources for t=0: inst g covers cols 4g..4g+3 of the strip
  const char* srcG[4];
  #pragma unroll
  for (int g = 0; g < 4; ++g) {
    const int cin = 4 * g + (lane >> 4);              // in-strip col 0..15
    const int col = strip * 16 + cin;                 // in-tile col
    srcG[g] = (const char*)Yq + (size_t)col * 256 + (((lane & 15) ^ (cin & 15)) << 4);
  }

  // prologue: stage Cs (block-wide, 4 KB per wave) + tiles 0,1 into halves
  #pragma unroll
  for (int g = 0; g < 4; ++g)
    __builtin_amdgcn_global_load_lds(
        (const AS1 uint32_t*)((const char*)cbuf + wid * 4096 + g * 1024 + lane * 16),
        (AS3 uint32_t*)(ldsB + CS_OFF + wid * 4096 + g * 1024), 16, 0, 0);
  STAGE(0, 0);
  STAGE(1, 4096);
  asm volatile("s_waitcnt vmcnt(0)" ::: "memory");
  __builtin_amdgcn_s_barrier();    // Cs visible to all waves (only loop-side barrier)

  int8v R0[2], R1[2];
  READF(R0, 0);                    // frags(0) -> CUR for body 0
  float cjA = *(const float*)(ldsB + CS_OFF + cjo), cjB;

  f32x4 vmin[4];
  #pragma unroll
  for (int m = 0; m < 4; ++m)
    vmin[m] = (f32x4){3.4e38f, 3.4e38f, 3.4e38f, 3.4e38f};

  #pragma unroll 1
  for (int tt = 0; tt < NT; tt += 2) {
    ITER(tt,     0,    R0, R1, cjA, cjB);
    ITER(tt + 1, 4096, R1, R0, cjB, cjA);
  }

  // epilogue: per-wave min over its 16 cols; merge strips via LDS; sum rows.
  // C/D layout: col = lane&15, row = (lane>>4)*4 + reg
  float* Rw = (float*)(ldsB + RW_OFF);   // [4 strips][128 rows]
  #pragma unroll
  for (int m = 0; m < 4; ++m) {
    #pragma unroll
    for (int r = 0; r < 4; ++r) {
      float v = vmin[m][r];
      v = fminf(v, __shfl_xor(v, 1));
      v = fminf(v, __shfl_xor(v, 2));
      v = fminf(v, __shfl_xor(v, 4));
      v = fminf(v, __shfl_xor(v, 8));
      vmin[m][r] = v;
    }
    if (c15 < 4) {
      float vsel = vmin[m][0];
      vsel = (c15 == 1) ? vmin[m][1] : vsel;
      vsel = (c15 == 2) ? vmin[m][2] : vsel;
      vsel = (c15 == 3) ? vmin[m][3] : vsel;
      Rw[strip * 128 + rg * 64 + m * 16 + w4 * 4 + c15] = vsel;
    }
  }
  __syncthreads();

  float* part = (float*)(ldsB + 100352);
  if (tid < BM) {
    float rm = fminf(fminf(Rw[tid], Rw[128 + tid]),
                     fminf(Rw[256 + tid], Rw[384 + tid]));
    float s = rm + xhalf[brow + tid];
    #pragma unroll
    for (int m = 32; m >= 1; m >>= 1) s += __shfl_xor(s, m);
    if (lane == 0) part[wid] = s;
  }
  __syncthreads();
  if (tid == 0) atomicAdd(sum_accum, part[0] + part[1]);
}

// ---- K3: out = sum/N + mean(psi)
__global__ void k_final(const float* __restrict__ psi, const float* __restrict__ sum_accum,
                        float* __restrict__ out)
{
  __shared__ float sh[4];
  float s = 0.f;
  for (int i = threadIdx.x; i < MCOLS; i += 256) s += psi[i];
  #pragma unroll
  for (int m = 32; m >= 1; m >>= 1) s += __shfl_xor(s, m);
  const int wid = threadIdx.x >> 6, lane = threadIdx.x & 63;
  if (lane == 0) sh[wid] = s;
  __syncthreads();
  if (threadIdx.x == 0)
    out[0] = sum_accum[0] / (float)NROWS + (sh[0] + sh[1] + sh[2] + sh[3]) / (float)MCOLS;
}

extern "C" void kernel_launch(void* const* d_in, const int* in_sizes, int n_in,
                              void* d_out, int out_size, void* d_ws, size_t ws_size,
                              hipStream_t stream)
{
  const float* X   = (const float*)d_in[0];
  const float* Y   = (const float*)d_in[1];
  const float* psi = (const float*)d_in[2];
  float* out = (float*)d_out;

  char* ws = (char*)d_ws;
  uint32_t* XqN    = (uint32_t*)(ws);                                           // 8,388,608 B
  uint32_t* Yq     = (uint32_t*)(ws + (size_t)NROWS * DDIM);                    // 2,097,152 B
  float* cbuf      = (float*)(ws + (size_t)(NROWS + MCOLS) * DDIM);             //    32,768 B
  float* xhalf     = (float*)((char*)cbuf + (size_t)MCOLS * 4);                 //   131,072 B
  float* sum_accum = (float*)((char*)xhalf + (size_t)NROWS * 4);                //         4 B

  k_prep <<<2048, 256, 0, stream>>>(X, Y, psi, XqN, Yq, xhalf, cbuf, sum_accum);
  k_gemm <<<NWG, 512, 0, stream>>>(XqN, Yq, cbuf, xhalf, sum_accum);
  k_final<<<1, 256, 0, stream>>>(psi, sum_accum, out);
}

// Round 20
// 77.931 us; speedup vs baseline: 1.0842x; 1.0842x over previous
//
#include <hip/hip_runtime.h>
#include <hip/hip_bf16.h>
#include <stdint.h>

#define NROWS 32768
#define MCOLS 8192
#define DDIM  256

#define BM 128            // rows per workgroup; block sweeps ALL cols
#define BN 64             // cols per iteration (4 strips x 16)
#define NT (MCOLS/BN)     // 128 iterations
#define NWG (NROWS/BM)    // 256 workgroups = 1 per CU

typedef __attribute__((ext_vector_type(8))) int   int8v;
typedef __attribute__((ext_vector_type(4))) int   int4v;
typedef __attribute__((ext_vector_type(4))) float f32x4;

#define AS1 __attribute__((address_space(1)))
#define AS3 __attribute__((address_space(3)))

// LDS map (bytes): [0,65536) = 8 waves x 8KB private dbuf B
//                  [65536,98304) = Cs (all 8192 cj)
//                  [98304,100352) = Rw[4][128] strip-min merge
#define CS_OFF 65536
#define RW_OFF 98304

// pack 4 f32 -> 4 fp8 e4m3 (OCP) via HW converter (RNE, saturating)
__device__ __forceinline__ uint32_t pk4_fp8(float4 v) {
  int p = __builtin_amdgcn_cvt_pk_fp8_f32(v.x, v.y, 0, false);
  p = __builtin_amdgcn_cvt_pk_fp8_f32(v.z, v.w, p, true);
  return (uint32_t)p;
}
__device__ __forceinline__ f32x4 vmin4(f32x4 x, f32x4 y) {
  f32x4 r;
  r[0] = fminf(x[0], y[0]); r[1] = fminf(x[1], y[1]);
  r[2] = fminf(x[2], y[2]); r[3] = fminf(x[3], y[3]);
  return r;
}

// ---- K1: prep. XqN = row-major fp8 NEGATED (acc C-init = cj -> cj - x.y);
//          Yq = row-major fp8; xhalf = 0.5||x||^2; cbuf = 0.5||y||^2 - psi.
__global__ void k_prep(const float* __restrict__ X, const float* __restrict__ Y,
                       const float* __restrict__ psi,
                       uint32_t* __restrict__ XqN, uint32_t* __restrict__ Yq,
                       float* __restrict__ xhalf, float* __restrict__ cbuf,
                       float* __restrict__ sum_accum)
{
  const int lane = threadIdx.x & 63;
  const int gw = (blockIdx.x * blockDim.x + threadIdx.x) >> 6;
  const int nw = (gridDim.x * blockDim.x) >> 6;
  for (int row = gw; row < NROWS + MCOLS; row += nw) {
    const bool isX = row < NROWS;
    const int r = isX ? row : row - NROWS;
    const float* src = isX ? (X + (size_t)row * DDIM) : (Y + (size_t)r * DDIM);
    float4 v = ((const float4*)src)[lane];
    const uint32_t pk = pk4_fp8(v);
    if (isX) XqN[(size_t)row * 64 + lane] = pk ^ 0x80808080u;   // negate fp8
    else     Yq[(size_t)r * 64 + lane] = pk;
    float s = v.x*v.x + v.y*v.y + v.z*v.z + v.w*v.w;
    #pragma unroll
    for (int m = 32; m >= 1; m >>= 1) s += __shfl_xor(s, m);
    if (lane == 0) {
      if (isX) xhalf[row] = 0.5f * s;
      else     cbuf[r] = 0.5f * s - psi[r];
    }
  }
  if (blockIdx.x == 0 && threadIdx.x == 0) sum_accum[0] = 0.0f;
}

// stage this wave's OWN 16-col strip of tile t_ (4 KB) into its private LDS
// half h_ (0/4096). XOR involution: LDS[c][q] = Yq[col][q ^ (c&15)]; dest
// linear (rule #21). srcG[g] precomputed per-lane for t=0; +t*16384 per tile.
#define STAGE(t_, h_) do {                                                      \
    _Pragma("unroll") for (int _g = 0; _g < 4; ++_g)                            \
      __builtin_amdgcn_global_load_lds(                                         \
          (const AS1 uint32_t*)(srcG[_g] + (size_t)(t_) * 16384),               \
          (AS3 uint32_t*)(ldsB + wbase + (h_) + _g * 1024), 16, 0, 0);          \
  } while (0)

// one body (r12 schedule): read own strip frags (4 b128) + cj; 8 MFMA with
// C-init = cj into ACC (NO vmin fold here); stage t_+2 into the half consumed.
#define ITERC(t_, h_, ACC) do {                                                 \
    asm volatile("s_waitcnt vmcnt(4)" ::: "memory");                            \
    int8v bf0, bf1;                                                             \
    {                                                                           \
      const char* _b = ldsB + wbase + (h_) + c15 * 256;                         \
      const int4v _l0 = *(const int4v*)(_b + (((w4 * 2 + 0) ^ c15) << 4));      \
      const int4v _h0 = *(const int4v*)(_b + (((w4 * 2 + 1) ^ c15) << 4));      \
      const int4v _l1 = *(const int4v*)(_b + (((8 + w4 * 2 + 0) ^ c15) << 4));  \
      const int4v _h1 = *(const int4v*)(_b + (((8 + w4 * 2 + 1) ^ c15) << 4));  \
      bf0 = (int8v){_l0[0],_l0[1],_l0[2],_l0[3],_h0[0],_h0[1],_h0[2],_h0[3]};   \
      bf1 = (int8v){_l1[0],_l1[1],_l1[2],_l1[3],_h1[0],_h1[1],_h1[2],_h1[3]};   \
    }                                                                           \
    const float cj = *(const float*)(ldsB + CS_OFF + (((t_) * 64) << 2) + cjo); \
    const f32x4 _ci = {cj, cj, cj, cj};                                         \
    _Pragma("unroll") for (int _m = 0; _m < 4; ++_m)                            \
      ACC[_m] = __builtin_amdgcn_mfma_scale_f32_16x16x128_f8f6f4(               \
          a[_m][0], bf0, _ci, 0, 0, 0, 0x7F, 0, 0x7F);                          \
    _Pragma("unroll") for (int _m = 0; _m < 4; ++_m)                            \
      ACC[_m] = __builtin_amdgcn_mfma_scale_f32_16x16x128_f8f6f4(               \
          a[_m][1], bf1, ACC[_m], 0, 0, 0, 0x7F, 0, 0x7F);                      \
    __builtin_amdgcn_sched_barrier(0);                                          \
    if ((t_) + 2 < NT) STAGE((t_) + 2, h_);                                     \
  } while (0)

// ---- K2: barrier-free main loop (r12 structure). 8 waves = 2 row-groups x 4
//          col-strips; A (64 rows) in regs; each wave stages its own strip
//          into private dbuf LDS; counted vmcnt only; pair-folded min3 vmin.
__global__ __attribute__((amdgpu_flat_work_group_size(512, 512),
                          amdgpu_waves_per_eu(2, 2)))
void k_gemm(const uint32_t* __restrict__ XqN, const uint32_t* __restrict__ Yq,
            const float* __restrict__ cbuf, const float* __restrict__ xhalf,
            float* __restrict__ sum_accum)
{
  __shared__ __align__(16) char ldsB[100352 + 8];

  const int brow = blockIdx.x * BM;
  const int tid  = threadIdx.x;
  const int wid  = tid >> 6;
  const int lane = tid & 63;
  const int rg    = wid >> 2;      // 0..1 -> rows rg*64
  const int strip = wid & 3;       // 0..3 -> cols strip*16 within each 64-tile
  const int c15 = lane & 15;
  const int w4  = lane >> 4;
  const int wbase = wid * 8192;    // private 8 KB dbuf
  const int cjo = (strip * 16 + c15) << 2;

  // A fragments (negated fp8): rows brow + rg*64 + m*16 + c15; bytes kc*128+w4*32
  int8v a[4][2];
  {
    const char* aBase = (const char*)XqN + ((size_t)(brow + rg * 64 + c15) << 8) + w4 * 32;
    #pragma unroll
    for (int m = 0; m < 4; ++m)
      #pragma unroll
      for (int kc = 0; kc < 2; ++kc)
        a[m][kc] = *(const int8v*)(aBase + m * 4096 + kc * 128);
  }

  // per-lane stage sources for t=0: inst g covers cols 4g..4g+3 of the strip
  const char* srcG[4];
  #pragma unroll
  for (int g = 0; g < 4; ++g) {
    const int cin = 4 * g + (lane >> 4);              // in-strip col 0..15
    const int col = strip * 16 + cin;                 // in-tile col
    srcG[g] = (const char*)Yq + (size_t)col * 256 + (((lane & 15) ^ (cin & 15)) << 4);
  }

  // prologue: stage Cs (block-wide, 4 KB per wave) + tiles 0,1 into halves
  #pragma unroll
  for (int g = 0; g < 4; ++g)
    __builtin_amdgcn_global_load_lds(
        (const AS1 uint32_t*)((const char*)cbuf + wid * 4096 + g * 1024 + lane * 16),
        (AS3 uint32_t*)(ldsB + CS_OFF + wid * 4096 + g * 1024), 16, 0, 0);
  STAGE(0, 0);
  STAGE(1, 4096);
  asm volatile("s_waitcnt vmcnt(0)" ::: "memory");
  __builtin_amdgcn_s_barrier();    // Cs visible to all waves (only loop-side barrier)

  f32x4 vmin[4];
  #pragma unroll
  for (int m = 0; m < 4; ++m)
    vmin[m] = (f32x4){3.4e38f, 3.4e38f, 3.4e38f, 3.4e38f};

  #pragma unroll 1
  for (int tt = 0; tt < NT; tt += 2) {
    f32x4 accP[4], accQ[4];
    ITERC(tt,     0,    accP);
    ITERC(tt + 1, 4096, accQ);
    // pair fold: nested fmin -> v_min3_f32 (16 min3 per pair vs 32 fmin)
    #pragma unroll
    for (int m = 0; m < 4; ++m)
      vmin[m] = vmin4(vmin4(vmin[m], accP[m]), accQ[m]);
  }

  // epilogue: per-wave min over its 16 cols; merge strips via LDS; sum rows.
  // C/D layout: col = lane&15, row = (lane>>4)*4 + reg
  float* Rw = (float*)(ldsB + RW_OFF);   // [4 strips][128 rows]
  #pragma unroll
  for (int m = 0; m < 4; ++m) {
    #pragma unroll
    for (int r = 0; r < 4; ++r) {
      float v = vmin[m][r];
      v = fminf(v, __shfl_xor(v, 1));
      v = fminf(v, __shfl_xor(v, 2));
      v = fminf(v, __shfl_xor(v, 4));
      v = fminf(v, __shfl_xor(v, 8));
      vmin[m][r] = v;
    }
    if (c15 < 4) {
      float vsel = vmin[m][0];
      vsel = (c15 == 1) ? vmin[m][1] : vsel;
      vsel = (c15 == 2) ? vmin[m][2] : vsel;
      vsel = (c15 == 3) ? vmin[m][3] : vsel;
      Rw[strip * 128 + rg * 64 + m * 16 + w4 * 4 + c15] = vsel;
    }
  }
  __syncthreads();

  float* part = (float*)(ldsB + 100352);
  if (tid < BM) {
    float rm = fminf(fminf(Rw[tid], Rw[128 + tid]),
                     fminf(Rw[256 + tid], Rw[384 + tid]));
    float s = rm + xhalf[brow + tid];
    #pragma unroll
    for (int m = 32; m >= 1; m >>= 1) s += __shfl_xor(s, m);
    if (lane == 0) part[wid] = s;
  }
  __syncthreads();
  if (tid == 0) atomicAdd(sum_accum, part[0] + part[1]);
}

// ---- K3: out = sum/N + mean(psi)
__global__ void k_final(const float* __restrict__ psi, const float* __restrict__ sum_accum,
                        float* __restrict__ out)
{
  __shared__ float sh[4];
  float s = 0.f;
  for (int i = threadIdx.x; i < MCOLS; i += 256) s += psi[i];
  #pragma unroll
  for (int m = 32; m >= 1; m >>= 1) s += __shfl_xor(s, m);
  const int wid = threadIdx.x >> 6, lane = threadIdx.x & 63;
  if (lane == 0) sh[wid] = s;
  __syncthreads();
  if (threadIdx.x == 0)
    out[0] = sum_accum[0] / (float)NROWS + (sh[0] + sh[1] + sh[2] + sh[3]) / (float)MCOLS;
}

extern "C" void kernel_launch(void* const* d_in, const int* in_sizes, int n_in,
                              void* d_out, int out_size, void* d_ws, size_t ws_size,
                              hipStream_t stream)
{
  const float* X   = (const float*)d_in[0];
  const float* Y   = (const float*)d_in[1];
  const float* psi = (const float*)d_in[2];
  float* out = (float*)d_out;

  char* ws = (char*)d_ws;
  uint32_t* XqN    = (uint32_t*)(ws);                                           // 8,388,608 B
  uint32_t* Yq     = (uint32_t*)(ws + (size_t)NROWS * DDIM);                    // 2,097,152 B
  float* cbuf      = (float*)(ws + (size_t)(NROWS + MCOLS) * DDIM);             //    32,768 B
  float* xhalf     = (float*)((char*)cbuf + (size_t)MCOLS * 4);                 //   131,072 B
  float* sum_accum = (float*)((char*)xhalf + (size_t)NROWS * 4);                //         4 B

  k_prep <<<2048, 256, 0, stream>>>(X, Y, psi, XqN, Yq, xhalf, cbuf, sum_accum);
  k_gemm <<<NWG, 512, 0, stream>>>(XqN, Yq, cbuf, xhalf, sum_accum);
  k_final<<<1, 256, 0, stream>>>(psi, sum_accum, out);
}